// Round 16
// baseline (6314.719 us; speedup 1.0000x reference)
//
#include <hip/hip_runtime.h>
#include <hip/hip_bf16.h>
#include <math.h>

#define SEQ   32
#define BATCH 1024
#define NN    19
#define HH    128
#define NB    4            /* batch elements per block */
#define MR    (NB*NN)      /* 76 rows per block */
#define SAS   264          /* sA row stride (bf16): 528 B = 16B-aligned, 4-bank shift */
#define HS    132          /* h row stride (elems) */
#define UTS2  40           /* Ut slab row stride (bf16): 80 B, 16B-aligned */
#define NBLK  (BATCH/NB)   /* 256 blocks, 1 per CU */
#define NT    512          /* 8 waves, 2 per SIMD -> 256 unified regs/wave */

#define OFF_G0 0
#define OFF_C0 122880
#define OFF_G1 184320
#define OFF_C1 380928
#define WTOT   479232      /* total weight elems (bf16) = 958 KB */

// Weights in module-scope device memory (coarse-grained, L2-cacheable).
__device__ unsigned short g_wall[WTOT];
__device__ unsigned short g_tg[3*1024];    // T'_j as three 32x32 bf16 mats

typedef __attribute__((ext_vector_type(8))) short  bf16x8;
typedef __attribute__((ext_vector_type(4))) float  f32x4;

__device__ __forceinline__ unsigned short f2bf(float v) {
    __hip_bfloat16 b = __float2bfloat16(v);
    return *reinterpret_cast<unsigned short*>(&b);
}
__device__ __forceinline__ float bf2f(unsigned short u) {
    unsigned int x = ((unsigned int)u) << 16;
    return __uint_as_float(x);
}
__device__ __forceinline__ float hload(const unsigned short* p) { return bf2f(*p); }
__device__ __forceinline__ float hload(const float* p)          { return *p; }
__device__ __forceinline__ void  hstore(unsigned short* p, float v) { *p = f2bf(v); }
__device__ __forceinline__ void  hstore(float* p, float v)          { *p = v; }

// ---------------------------------------------------------------------------
// Setup 1: weight reorder/transpose into g_wall.
// ---------------------------------------------------------------------------
__global__ __launch_bounds__(256) void wconv_kernel(
    const float* __restrict__ W, int F, int O, int KP, int off)
{
    int idx = blockIdx.x*256 + threadIdx.x;
    int total = 3*O*KP;
    if (idx >= total) return;
    int j   = idx / (O*KP);
    int r   = idx - j*(O*KP);
    int col = r / KP;
    int k   = r - col*KP;
    float v = (k < F) ? W[(size_t)(j*F + k)*O + col] : 0.f;
    g_wall[off + idx] = f2bf(v);
}

// ---------------------------------------------------------------------------
// Setup 2: T'_j as three 32x32 bf16 mats: g_tg[j][m][n] = Tj[m,n] (0-padded).
// T0=I, T1=S, T2=2S^2-I.
// ---------------------------------------------------------------------------
__global__ __launch_bounds__(256) void tprime_kernel(const float* __restrict__ S)
{
    __shared__ float sS[NN*NN], sS2[NN*NN];
    int tid = threadIdx.x;
    for (int i = tid; i < NN*NN; i += 256) sS[i] = S[i];
    __syncthreads();
    for (int i = tid; i < NN*NN; i += 256) {
        int m = i/NN, n = i - m*NN;
        float a = 0.f;
        for (int k = 0; k < NN; ++k) a += sS[m*NN+k]*sS[k*NN+n];
        sS2[i] = a;
    }
    __syncthreads();
    for (int i = tid; i < 3*32*32; i += 256) {
        int j = i >> 10, r = i & 1023;
        int m = r >> 5, n = r & 31;
        float v = 0.f;
        if (m < NN && n < NN) {
            float eye = (m == n) ? 1.f : 0.f;
            if (j == 0)      v = eye;
            else if (j == 1) v = sS[m*NN+n];
            else             v = 2.f*sS2[m*NN+n] - eye;
        }
        g_tg[i] = f2bf(v);
    }
}

// ---------------------------------------------------------------------------
// Persistent kernel: 256 blocks x 512 threads (8 waves, 2/SIMD).
// LDS: h0 bf16 | h1 f32 | sA | ub | Ut(8 x 32x40) | xprev = 143,280 B
// ---------------------------------------------------------------------------
#define LDS_BYTES 143280

template<int KS, int NTC, bool GATE, int XW, typename HT>
__device__ __forceinline__ void gconv_phase(
    const unsigned short* __restrict__ BT,   // (3, OC=NTC*128, KS*32) bf16
    const float* __restrict__ bias,
    HT* hL,
    unsigned short* sA,
    unsigned short* ub,
    unsigned short* UtW,                     // this wave's slab (32 x UTS2)
    int lane, int w)
{
    constexpr int OC = NTC*128;
    constexpr int KP = KS*32;
    const int r16 = lane & 15, quad = lane >> 4;
    const int sgo = w * (NTC*16);
    const unsigned short* lanep = BT + (size_t)(sgo + r16)*KP + quad*8;

    // per-batch mixed accumulators, persist across j
    f32x4 y[NB][2][NTC];
    #pragma unroll
    for (int b = 0; b < NB; ++b)
        #pragma unroll
        for (int a = 0; a < 2; ++a)
            #pragma unroll
            for (int nt = 0; nt < NTC; ++nt) y[b][a][nt] = (f32x4)0.f;

    #pragma unroll
    for (int j = 0; j < 3; ++j) {
        // burst-load ALL of j's weight fragments (KS*NTC independent loads)
        bf16x8 bf[KS][NTC];
        #pragma unroll
        for (int ks = 0; ks < KS; ++ks)
            #pragma unroll
            for (int nt = 0; nt < NTC; ++nt)
                bf[ks][nt] = *(const bf16x8*)(lanep +
                    (size_t)(j*OC + nt*16)*KP + ks*32);

        f32x4 acc[5][NTC];
        #pragma unroll
        for (int mt = 0; mt < 5; ++mt)
            #pragma unroll
            for (int nt = 0; nt < NTC; ++nt) acc[mt][nt] = (f32x4)0.f;

        #pragma unroll
        for (int ks = 0; ks < KS; ++ks)
            #pragma unroll
            for (int mt = 0; mt < 5; ++mt) {
                bf16x8 af = *(const bf16x8*)&sA[(mt*16 + r16)*SAS + ks*32 + quad*8];
                #pragma unroll
                for (int nt = 0; nt < NTC; ++nt)
                    acc[mt][nt] = __builtin_amdgcn_mfma_f32_16x16x32_bf16(
                        af, bf[ks][nt], acc[mt][nt], 0, 0, 0);
            }

        // T'_j A-fragments (32x32, K=32)
        bf16x8 tpj0 = *(const bf16x8*)&g_tg[j*1024 + r16*32 + quad*8];
        bf16x8 tpj1 = *(const bf16x8*)&g_tg[j*1024 + (16 + r16)*32 + quad*8];

        #pragma unroll
        for (int b = 0; b < NB; ++b) {
            // scatter U_jb into the wave slab (row = out col, col = node n)
            #pragma unroll
            for (int mt = 0; mt < 5; ++mt)
                #pragma unroll
                for (int reg = 0; reg < 4; ++reg) {
                    int gm = mt*16 + quad*4 + reg;
                    int n  = gm - b*NN;
                    if (n >= 0 && n < NN) {
                        #pragma unroll
                        for (int nt = 0; nt < NTC; ++nt)
                            UtW[(nt*16 + r16)*UTS2 + n] = f2bf(acc[mt][nt][reg]);
                    }
                }
            // mix-accumulate: y[b] += T'_j @ U_jb   (K=32)
            #pragma unroll
            for (int nt = 0; nt < NTC; ++nt) {
                bf16x8 uf = *(const bf16x8*)&UtW[(nt*16 + r16)*UTS2 + quad*8];
                y[b][0][nt] = __builtin_amdgcn_mfma_f32_16x16x32_bf16(
                    tpj0, uf, y[b][0][nt], 0, 0, 0);
                y[b][1][nt] = __builtin_amdgcn_mfma_f32_16x16x32_bf16(
                    tpj1, uf, y[b][1][nt], 0, 0, 0);
            }
        }
    }

    if (GATE) __syncthreads();   // gate epilogue rewrites sA (r*h)

    float bv[NTC];
    #pragma unroll
    for (int nt = 0; nt < NTC; ++nt) bv[nt] = bias[sgo + nt*16 + r16];

    #pragma unroll
    for (int b = 0; b < NB; ++b)
        #pragma unroll
        for (int mt2 = 0; mt2 < 2; ++mt2)
            #pragma unroll
            for (int nt = 0; nt < NTC; ++nt)
                #pragma unroll
                for (int reg = 0; reg < 4; ++reg) {
                    int m = mt2*16 + quad*4 + reg;
                    if (m < NN) {
                        int o = sgo + nt*16 + r16;
                        float v = y[b][mt2][nt][reg] + bv[nt];
                        int row = b*NN + m;
                        if (GATE) {
                            float sg_ = 1.f/(1.f + __expf(-v));
                            if (o < HH)
                                sA[row*SAS + XW + o] =
                                    f2bf(sg_ * hload(&hL[row*HS + o]));
                            else
                                ub[row*HS + (o-HH)] = f2bf(sg_);
                        } else {
                            float c  = 2.f/(1.f + __expf(-2.f*v)) - 1.f;
                            float u  = bf2f(ub[row*HS + o]);
                            float ho = hload(&hL[row*HS + o]);
                            hstore(&hL[row*HS + o], u*ho + (1.f - u)*c);
                        }
                    }
                }
}

__global__ __launch_bounds__(NT, 2) void dcgru_persistent(
    const float* __restrict__ ihs,
    const float* __restrict__ bg0, const float* __restrict__ bc0,
    const float* __restrict__ bg1, const float* __restrict__ bc1,
    const float* __restrict__ Wp, const float* __restrict__ bp,
    float* __restrict__ out)
{
    extern __shared__ char smem[];
    unsigned short* h0    = (unsigned short*)smem;                 // 20064
    float*          h1    = (float*)(smem + 20064);                // 40128
    unsigned short* sA    = (unsigned short*)(smem + 60192);       // 42240
    unsigned short* ub    = (unsigned short*)(smem + 102432);      // 20064
    unsigned short* Ut    = (unsigned short*)(smem + 122496);      // 8*32*40*2 = 20480
    float*          xprev = (float*)(smem + 142976);               // 304

    const int tid  = threadIdx.x;
    const int lane = tid & 63;
    const int w    = tid >> 6;          // 0..7
    const int bb   = blockIdx.x * NB;
    unsigned short* UtW = Ut + w*32*UTS2;

    const unsigned short* BTg0 = g_wall + OFF_G0;
    const unsigned short* BTc0 = g_wall + OFF_C0;
    const unsigned short* BTg1 = g_wall + OFF_G1;
    const unsigned short* BTc1 = g_wall + OFF_C1;

    for (int i = tid; i < MR*HH; i += NT) {
        int row = i >> 7, f = i & 127;
        h0[row*HS + f] = f2bf(ihs[(size_t)bb*2432 + i]);
        h1[row*HS + f] = ihs[(size_t)(BATCH + bb)*2432 + i];
    }
    for (int i = tid; i < MR; i += NT) xprev[i] = 0.f;
    for (int i = lane; i < 32*UTS2; i += 64) UtW[i] = 0;   // incl. n-pad cols

    const float wp0 = Wp[lane], wp1 = Wp[64 + lane], bpv = bp[0];
    __syncthreads();

    for (int t = 0; t < SEQ; ++t) {
        // ---- layer 0: sA = [xprev | h0 | 0-pad]  (K = 160) ----
        for (int idx = tid; idx < MR*160; idx += NT) {
            int row = idx/160, c = idx - row*160;
            unsigned short v;
            if (c == 0)       v = f2bf(xprev[row]);
            else if (c <= HH) v = h0[row*HS + (c-1)];
            else              v = 0;
            sA[row*SAS + c] = v;
        }
        __syncthreads();
        gconv_phase<5,2,true ,1>(BTg0, bg0, h0, sA, ub, UtW, lane, w);
        __syncthreads();
        gconv_phase<5,1,false,1>(BTc0, bc0, h0, sA, ub, UtW, lane, w);
        __syncthreads();

        // ---- layer 1: sA = [h0 | h1]  (K = 256) ----
        for (int idx = tid; idx < MR*256; idx += NT) {
            int row = idx >> 8, c = idx & 255;
            sA[row*SAS + c] = (c < HH) ? h0[row*HS + c]
                                       : f2bf(h1[row*HS + (c-HH)]);
        }
        __syncthreads();
        gconv_phase<8,2,true ,HH>(BTg1, bg1, h1, sA, ub, UtW, lane, w);
        __syncthreads();
        gconv_phase<8,1,false,HH>(BTc1, bc1, h1, sA, ub, UtW, lane, w);
        __syncthreads();

        // ---- projection: wave w -> batch w>>1, half the nodes ----
        {
            int b  = w >> 1;
            int n0 = (w & 1) ? 10 : 0;
            int n1 = (w & 1) ? 19 : 10;
            for (int n = n0; n < n1; ++n) {
                int row = b*NN + n;
                float s = h1[row*HS + lane]*wp0 + h1[row*HS + 64 + lane]*wp1;
                #pragma unroll
                for (int off = 32; off; off >>= 1) s += __shfl_down(s, off, 64);
                if (lane == 0) {
                    float v = s + bpv;
                    out[((size_t)t*BATCH + bb + b)*NN + n] = v;
                    xprev[row] = v;
                }
            }
        }
        __syncthreads();
    }
}

// ---------------------------------------------------------------------------
extern "C" void kernel_launch(void* const* d_in, const int* in_sizes, int n_in,
                              void* d_out, int out_size, void* d_ws, size_t ws_size,
                              hipStream_t stream) {
    const float* ihs = (const float*)d_in[1];
    const float* S   = (const float*)d_in[2];
    const float* Wg0 = (const float*)d_in[3];
    const float* bg0 = (const float*)d_in[4];
    const float* Wc0 = (const float*)d_in[5];
    const float* bc0 = (const float*)d_in[6];
    const float* Wg1 = (const float*)d_in[7];
    const float* bg1 = (const float*)d_in[8];
    const float* Wc1 = (const float*)d_in[9];
    const float* bc1 = (const float*)d_in[10];
    const float* Wp  = (const float*)d_in[11];
    const float* bp  = (const float*)d_in[12];
    float* out = (float*)d_out;

    tprime_kernel<<<1, 256, 0, stream>>>(S);
    wconv_kernel<<<(3*256*160+255)/256, 256, 0, stream>>>(Wg0, 129, 256, 160, OFF_G0);
    wconv_kernel<<<(3*128*160+255)/256, 256, 0, stream>>>(Wc0, 129, 128, 160, OFF_C0);
    wconv_kernel<<<(3*256*256+255)/256, 256, 0, stream>>>(Wg1, 256, 256, 256, OFF_G1);
    wconv_kernel<<<(3*128*256+255)/256, 256, 0, stream>>>(Wc1, 256, 128, 256, OFF_C1);

    hipFuncSetAttribute((const void*)dcgru_persistent,
                        hipFuncAttributeMaxDynamicSharedMemorySize, LDS_BYTES);

    dcgru_persistent<<<NBLK, NT, LDS_BYTES, stream>>>(
        ihs, bg0, bc0, bg1, bc1, Wp, bp, out);
}

// Round 17
// 2900.777 us; speedup vs baseline: 2.1769x; 2.1769x over previous
//
#include <hip/hip_runtime.h>
#include <hip/hip_bf16.h>
#include <math.h>

#define SEQ   32
#define BATCH 1024
#define NN    19
#define HH    128
#define NB    4            /* batch elements per block */
#define MR    (NB*NN)      /* 76 rows per block */
#define SAS   264          /* sA row stride (bf16): 528 B = 16B-aligned, 4-bank shift */
#define HS    132          /* h row stride (elems) */
#define UTS   72           /* Ut row stride (bf16): 144 B = 16B-aligned rows */
#define NBLK  (BATCH/NB)   /* 256 blocks, 1 per CU */
#define NT    512          /* 8 waves, 2 per SIMD -> 256 unified regs/wave */

#define OFF_G0 0
#define OFF_C0 122880
#define OFF_G1 184320
#define OFF_C1 380928
#define WTOT   479232      /* total weight elems (bf16) = 958 KB */

// Weights in module-scope device memory (coarse-grained, L2-cacheable).
__device__ unsigned short g_wall[WTOT];
__device__ unsigned short g_tg[2048];

typedef __attribute__((ext_vector_type(8))) short  bf16x8;
typedef __attribute__((ext_vector_type(4))) float  f32x4;

__device__ __forceinline__ unsigned short f2bf(float v) {
    __hip_bfloat16 b = __float2bfloat16(v);
    return *reinterpret_cast<unsigned short*>(&b);
}
__device__ __forceinline__ float bf2f(unsigned short u) {
    unsigned int x = ((unsigned int)u) << 16;
    return __uint_as_float(x);
}
__device__ __forceinline__ float hload(const unsigned short* p) { return bf2f(*p); }
__device__ __forceinline__ float hload(const float* p)          { return *p; }
__device__ __forceinline__ void  hstore(unsigned short* p, float v) { *p = f2bf(v); }
__device__ __forceinline__ void  hstore(float* p, float v)          { *p = v; }

// ---------------------------------------------------------------------------
// Setup 1: weight reorder/transpose into g_wall.
// ---------------------------------------------------------------------------
__global__ __launch_bounds__(256) void wconv_kernel(
    const float* __restrict__ W, int F, int O, int KP, int off)
{
    int idx = blockIdx.x*256 + threadIdx.x;
    int total = 3*O*KP;
    if (idx >= total) return;
    int j   = idx / (O*KP);
    int r   = idx - j*(O*KP);
    int col = r / KP;
    int k   = r - col*KP;
    float v = (k < F) ? W[(size_t)(j*F + k)*O + col] : 0.f;
    g_wall[off + idx] = f2bf(v);
}

// ---------------------------------------------------------------------------
// Setup 2: T' (32 x 64) bf16: T'[m][j*19+n] = Tj[m,n]; T0=I, T1=S, T2=2S^2-I.
// ---------------------------------------------------------------------------
__global__ __launch_bounds__(256) void tprime_kernel(const float* __restrict__ S)
{
    __shared__ float sS[NN*NN], sS2[NN*NN];
    int tid = threadIdx.x;
    for (int i = tid; i < NN*NN; i += 256) sS[i] = S[i];
    __syncthreads();
    for (int i = tid; i < NN*NN; i += 256) {
        int m = i/NN, n = i - m*NN;
        float a = 0.f;
        for (int k = 0; k < NN; ++k) a += sS[m*NN+k]*sS[k*NN+n];
        sS2[i] = a;
    }
    __syncthreads();
    for (int i = tid; i < 32*64; i += 256) {
        int m = i >> 6, k = i & 63;
        float v = 0.f;
        if (m < NN && k < 3*NN) {
            int j = k / NN, n = k - j*NN;
            float eye = (m == n) ? 1.f : 0.f;
            if (j == 0)      v = eye;
            else if (j == 1) v = sS[m*NN+n];
            else             v = 2.f*sS2[m*NN+n] - eye;
        }
        g_tg[i] = f2bf(v);
    }
}

// ---------------------------------------------------------------------------
// Persistent kernel: 256 blocks x 512 threads (8 waves, 2/SIMD).
// LDS: h0 bf16 | h1 f32 | sA | ub | Ut(8 slabs x 32 rows) | xprev = 159,664 B
// ---------------------------------------------------------------------------
#define LDS_BYTES 159664

template<int KS, int NTC, bool GATE, int XW, typename HT>
__device__ __forceinline__ void gconv_phase(
    const unsigned short* __restrict__ BT,   // (3, OC=NTC*128, KS*32) bf16
    const float* __restrict__ bias,
    HT* hL,
    unsigned short* sA,
    unsigned short* ub,
    unsigned short* UtW,                     // this wave's slab (32 x UTS)
    int lane, int w)
{
    constexpr int OC = NTC*128;
    constexpr int KP = KS*32;
    const int r16 = lane & 15, quad = lane >> 4;
    const int sgo = w * (NTC*16);

    // single lane-varying base; (j,nt,ks) offsets are compile-time constants
    const unsigned short* lanep = BT + (size_t)(sgo + r16)*KP + quad*8;

    f32x4 acc[3][5][NTC];
    #pragma unroll
    for (int j = 0; j < 3; ++j)
        #pragma unroll
        for (int mt = 0; mt < 5; ++mt)
            #pragma unroll
            for (int nt = 0; nt < NTC; ++nt) acc[j][mt][nt] = (f32x4)0.f;

    // depth-2 ks ring; MFMA consumes ring slot directly, refill after use
    bf16x8 ring[2][3][NTC];
    #pragma unroll
    for (int j = 0; j < 3; ++j)
        #pragma unroll
        for (int nt = 0; nt < NTC; ++nt) {
            ring[0][j][nt] = *(const bf16x8*)(lanep + (size_t)(j*OC + nt*16)*KP);
            if (KS > 1)
                ring[1][j][nt] = *(const bf16x8*)(lanep + (size_t)(j*OC + nt*16)*KP + 32);
        }

    #pragma unroll
    for (int ks = 0; ks < KS; ++ks) {
        #pragma unroll
        for (int mt = 0; mt < 5; ++mt) {
            bf16x8 af = *(const bf16x8*)&sA[(mt*16 + r16)*SAS + ks*32 + quad*8];
            #pragma unroll
            for (int j = 0; j < 3; ++j)
                #pragma unroll
                for (int nt = 0; nt < NTC; ++nt)
                    acc[j][mt][nt] = __builtin_amdgcn_mfma_f32_16x16x32_bf16(
                        af, ring[ks & 1][j][nt], acc[j][mt][nt], 0, 0, 0);
        }
        if (ks + 2 < KS) {
            #pragma unroll
            for (int j = 0; j < 3; ++j)
                #pragma unroll
                for (int nt = 0; nt < NTC; ++nt)
                    ring[ks & 1][j][nt] = *(const bf16x8*)(lanep +
                        (size_t)(j*OC + nt*16)*KP + (ks + 2)*32);
        }
    }

    if (GATE) __syncthreads();   // gate epilogue rewrites sA (r*h)

    float bv[NTC];
    #pragma unroll
    for (int nt = 0; nt < NTC; ++nt) bv[nt] = bias[sgo + nt*16 + r16];

    // T' fragments read here (not held across the K loop)
    bf16x8 tp[2][2];
    #pragma unroll
    for (int mt2 = 0; mt2 < 2; ++mt2)
        #pragma unroll
        for (int kk = 0; kk < 2; ++kk)
            tp[mt2][kk] = *(const bf16x8*)&g_tg[(mt2*16 + r16)*64 + kk*32 + quad*8];

    for (int b = 0; b < NB; ++b) {
        // scatter this batch's node rows into Ut (row = out col, col = j*19+n)
        #pragma unroll
        for (int j = 0; j < 3; ++j)
            #pragma unroll
            for (int mt = 0; mt < 5; ++mt)
                #pragma unroll
                for (int reg = 0; reg < 4; ++reg) {
                    int gm = mt*16 + quad*4 + reg;
                    int n  = gm - b*NN;
                    if (n >= 0 && n < NN) {
                        #pragma unroll
                        for (int nt = 0; nt < NTC; ++nt)
                            UtW[(nt*16 + r16)*UTS + j*NN + n] =
                                f2bf(acc[j][mt][nt][reg]);
                    }
                }
        // mixing: y = T' @ U
        f32x4 y[2][NTC];
        #pragma unroll
        for (int a = 0; a < 2; ++a)
            #pragma unroll
            for (int c = 0; c < NTC; ++c) y[a][c] = (f32x4)0.f;
        #pragma unroll
        for (int kk = 0; kk < 2; ++kk)
            #pragma unroll
            for (int nt = 0; nt < NTC; ++nt) {
                bf16x8 uf = *(const bf16x8*)&UtW[(nt*16 + r16)*UTS + kk*32 + quad*8];
                y[0][nt] = __builtin_amdgcn_mfma_f32_16x16x32_bf16(
                    tp[0][kk], uf, y[0][nt], 0, 0, 0);
                y[1][nt] = __builtin_amdgcn_mfma_f32_16x16x32_bf16(
                    tp[1][kk], uf, y[1][nt], 0, 0, 0);
            }
        // epilogue
        #pragma unroll
        for (int mt2 = 0; mt2 < 2; ++mt2)
            #pragma unroll
            for (int nt = 0; nt < NTC; ++nt)
                #pragma unroll
                for (int reg = 0; reg < 4; ++reg) {
                    int m = mt2*16 + quad*4 + reg;
                    if (m < NN) {
                        int o = sgo + nt*16 + r16;
                        float v = y[mt2][nt][reg] + bv[nt];
                        int row = b*NN + m;
                        if (GATE) {
                            float sg_ = 1.f/(1.f + __expf(-v));
                            if (o < HH)
                                sA[row*SAS + XW + o] =
                                    f2bf(sg_ * hload(&hL[row*HS + o]));
                            else
                                ub[row*HS + (o-HH)] = f2bf(sg_);
                        } else {
                            float c  = 2.f/(1.f + __expf(-2.f*v)) - 1.f;
                            float u  = bf2f(ub[row*HS + o]);
                            float ho = hload(&hL[row*HS + o]);
                            hstore(&hL[row*HS + o], u*ho + (1.f - u)*c);
                        }
                    }
                }
    }
}

__global__ __launch_bounds__(NT, 2) void dcgru_persistent(
    const float* __restrict__ ihs,
    const float* __restrict__ bg0, const float* __restrict__ bc0,
    const float* __restrict__ bg1, const float* __restrict__ bc1,
    const float* __restrict__ Wp, const float* __restrict__ bp,
    float* __restrict__ out)
{
    extern __shared__ char smem[];
    unsigned short* h0    = (unsigned short*)smem;                 // 20064
    float*          h1    = (float*)(smem + 20064);                // 40128
    unsigned short* sA    = (unsigned short*)(smem + 60192);       // 42240
    unsigned short* ub    = (unsigned short*)(smem + 102432);      // 20064
    unsigned short* Ut    = (unsigned short*)(smem + 122496);      // 36864
    float*          xprev = (float*)(smem + 159360);               // 304

    const int tid  = threadIdx.x;
    const int lane = tid & 63;
    const int w    = tid >> 6;          // 0..7
    const int bb   = blockIdx.x * NB;
    unsigned short* UtW = Ut + w*32*UTS;

    const unsigned short* BTg0 = g_wall + OFF_G0;
    const unsigned short* BTc0 = g_wall + OFF_C0;
    const unsigned short* BTg1 = g_wall + OFF_G1;
    const unsigned short* BTc1 = g_wall + OFF_C1;

    for (int i = tid; i < MR*HH; i += NT) {
        int row = i >> 7, f = i & 127;
        h0[row*HS + f] = f2bf(ihs[(size_t)bb*2432 + i]);
        h1[row*HS + f] = ihs[(size_t)(BATCH + bb)*2432 + i];
    }
    for (int i = tid; i < MR; i += NT) xprev[i] = 0.f;
    for (int i = lane; i < 32*UTS; i += 64) UtW[i] = 0;

    const float wp0 = Wp[lane], wp1 = Wp[64 + lane], bpv = bp[0];
    __syncthreads();

    for (int t = 0; t < SEQ; ++t) {
        // ---- layer 0: sA = [xprev | h0 | 0-pad]  (K = 160) ----
        for (int idx = tid; idx < MR*160; idx += NT) {
            int row = idx/160, c = idx - row*160;
            unsigned short v;
            if (c == 0)       v = f2bf(xprev[row]);
            else if (c <= HH) v = h0[row*HS + (c-1)];
            else              v = 0;
            sA[row*SAS + c] = v;
        }
        __syncthreads();
        gconv_phase<5,2,true ,1>(BTg0, bg0, h0, sA, ub, UtW, lane, w);
        __syncthreads();
        gconv_phase<5,1,false,1>(BTc0, bc0, h0, sA, ub, UtW, lane, w);
        __syncthreads();

        // ---- layer 1: sA = [h0 | h1]  (K = 256) ----
        for (int idx = tid; idx < MR*256; idx += NT) {
            int row = idx >> 8, c = idx & 255;
            sA[row*SAS + c] = (c < HH) ? h0[row*HS + c]
                                       : f2bf(h1[row*HS + (c-HH)]);
        }
        __syncthreads();
        gconv_phase<8,2,true ,HH>(BTg1, bg1, h1, sA, ub, UtW, lane, w);
        __syncthreads();
        gconv_phase<8,1,false,HH>(BTc1, bc1, h1, sA, ub, UtW, lane, w);
        __syncthreads();

        // ---- projection: wave w -> batch w>>1, half the nodes ----
        {
            int b  = w >> 1;
            int n0 = (w & 1) ? 10 : 0;
            int n1 = (w & 1) ? 19 : 10;
            for (int n = n0; n < n1; ++n) {
                int row = b*NN + n;
                float s = h1[row*HS + lane]*wp0 + h1[row*HS + 64 + lane]*wp1;
                #pragma unroll
                for (int off = 32; off; off >>= 1) s += __shfl_down(s, off, 64);
                if (lane == 0) {
                    float v = s + bpv;
                    out[((size_t)t*BATCH + bb + b)*NN + n] = v;
                    xprev[row] = v;
                }
            }
        }
        __syncthreads();
    }
}

// ---------------------------------------------------------------------------
extern "C" void kernel_launch(void* const* d_in, const int* in_sizes, int n_in,
                              void* d_out, int out_size, void* d_ws, size_t ws_size,
                              hipStream_t stream) {
    const float* ihs = (const float*)d_in[1];
    const float* S   = (const float*)d_in[2];
    const float* Wg0 = (const float*)d_in[3];
    const float* bg0 = (const float*)d_in[4];
    const float* Wc0 = (const float*)d_in[5];
    const float* bc0 = (const float*)d_in[6];
    const float* Wg1 = (const float*)d_in[7];
    const float* bg1 = (const float*)d_in[8];
    const float* Wc1 = (const float*)d_in[9];
    const float* bc1 = (const float*)d_in[10];
    const float* Wp  = (const float*)d_in[11];
    const float* bp  = (const float*)d_in[12];
    float* out = (float*)d_out;

    tprime_kernel<<<1, 256, 0, stream>>>(S);
    wconv_kernel<<<(3*256*160+255)/256, 256, 0, stream>>>(Wg0, 129, 256, 160, OFF_G0);
    wconv_kernel<<<(3*128*160+255)/256, 256, 0, stream>>>(Wc0, 129, 128, 160, OFF_C0);
    wconv_kernel<<<(3*256*256+255)/256, 256, 0, stream>>>(Wg1, 256, 256, 256, OFF_G1);
    wconv_kernel<<<(3*128*256+255)/256, 256, 0, stream>>>(Wc1, 256, 128, 256, OFF_C1);

    hipFuncSetAttribute((const void*)dcgru_persistent,
                        hipFuncAttributeMaxDynamicSharedMemorySize, LDS_BYTES);

    dcgru_persistent<<<NBLK, NT, LDS_BYTES, stream>>>(
        ihs, bg0, bc0, bg1, bc1, Wp, bp, out);
}

// Round 18
// 2438.299 us; speedup vs baseline: 2.5898x; 1.1897x over previous
//
#include <hip/hip_runtime.h>
#include <hip/hip_bf16.h>
#include <math.h>

#define SEQ   32
#define BATCH 1024
#define NN    19
#define HH    128
#define NB    4            /* batch elements per block */
#define MR    (NB*NN)      /* 76 rows per block */
#define SAS   264          /* sA row stride (bf16): 528 B = 16B-aligned, 4-bank shift */
#define HS    132          /* h row stride (elems) */
#define UTS   72           /* Ut row stride (bf16): 144 B = 16B-aligned rows */
#define NBLK  (BATCH/NB)   /* 256 blocks, 1 per CU */
#define NT    512          /* 8 waves, 2 per SIMD -> 256 unified regs/wave */

#define OFF_G0 0
#define OFF_C0 122880
#define OFF_G1 184320
#define OFF_C1 380928
#define WTOT   479232      /* total weight elems (bf16) = 958 KB */

// Weights in module-scope device memory (coarse-grained, L2-cacheable).
__device__ unsigned short g_wall[WTOT];
__device__ unsigned short g_tg[2048];

typedef __attribute__((ext_vector_type(8))) short  bf16x8;
typedef __attribute__((ext_vector_type(4))) float  f32x4;

__device__ __forceinline__ unsigned short f2bf(float v) {
    __hip_bfloat16 b = __float2bfloat16(v);
    return *reinterpret_cast<unsigned short*>(&b);
}
__device__ __forceinline__ float bf2f(unsigned short u) {
    unsigned int x = ((unsigned int)u) << 16;
    return __uint_as_float(x);
}
__device__ __forceinline__ float hload(const unsigned short* p) { return bf2f(*p); }
__device__ __forceinline__ float hload(const float* p)          { return *p; }
__device__ __forceinline__ void  hstore(unsigned short* p, float v) { *p = f2bf(v); }
__device__ __forceinline__ void  hstore(float* p, float v)          { *p = v; }

// ---------------------------------------------------------------------------
// Setup 1: weight reorder/transpose into g_wall.
// ---------------------------------------------------------------------------
__global__ __launch_bounds__(256) void wconv_kernel(
    const float* __restrict__ W, int F, int O, int KP, int off)
{
    int idx = blockIdx.x*256 + threadIdx.x;
    int total = 3*O*KP;
    if (idx >= total) return;
    int j   = idx / (O*KP);
    int r   = idx - j*(O*KP);
    int col = r / KP;
    int k   = r - col*KP;
    float v = (k < F) ? W[(size_t)(j*F + k)*O + col] : 0.f;
    g_wall[off + idx] = f2bf(v);
}

// ---------------------------------------------------------------------------
// Setup 2: T' (32 x 64) bf16: T'[m][j*19+n] = Tj[m,n]; T0=I, T1=S, T2=2S^2-I.
// ---------------------------------------------------------------------------
__global__ __launch_bounds__(256) void tprime_kernel(const float* __restrict__ S)
{
    __shared__ float sS[NN*NN], sS2[NN*NN];
    int tid = threadIdx.x;
    for (int i = tid; i < NN*NN; i += 256) sS[i] = S[i];
    __syncthreads();
    for (int i = tid; i < NN*NN; i += 256) {
        int m = i/NN, n = i - m*NN;
        float a = 0.f;
        for (int k = 0; k < NN; ++k) a += sS[m*NN+k]*sS[k*NN+n];
        sS2[i] = a;
    }
    __syncthreads();
    for (int i = tid; i < 32*64; i += 256) {
        int m = i >> 6, k = i & 63;
        float v = 0.f;
        if (m < NN && k < 3*NN) {
            int j = k / NN, n = k - j*NN;
            float eye = (m == n) ? 1.f : 0.f;
            if (j == 0)      v = eye;
            else if (j == 1) v = sS[m*NN+n];
            else             v = 2.f*sS2[m*NN+n] - eye;
        }
        g_tg[i] = f2bf(v);
    }
}

// ---------------------------------------------------------------------------
// Persistent kernel: 256 blocks x 512 threads (8 waves, 2/SIMD).
// LDS: h0 bf16 | h1 f32 | sA | ub | Ut(8 slabs x 32 rows) | xprev = 159,664 B
// ---------------------------------------------------------------------------
#define LDS_BYTES 159664

template<int KS, int NTC, bool GATE, int XW, typename HT>
__device__ __forceinline__ void gconv_phase(
    const unsigned short* __restrict__ BT,   // (3, OC=NTC*128, KS*32) bf16
    const float* __restrict__ bias,
    HT* hL,
    unsigned short* sA,
    unsigned short* ub,
    unsigned short* UtW,                     // this wave's slab (32 x UTS)
    int lane, int w)
{
    constexpr int OC = NTC*128;
    constexpr int KP = KS*32;
    const int r16 = lane & 15, quad = lane >> 4;
    const int sgo = w * (NTC*16);

    const unsigned short* wb[3][NTC];
    #pragma unroll
    for (int j = 0; j < 3; ++j)
        #pragma unroll
        for (int nt = 0; nt < NTC; ++nt)
            wb[j][nt] = BT + (size_t)(j*OC + sgo + nt*16 + r16)*KP + quad*8;

    f32x4 acc[3][5][NTC];
    #pragma unroll
    for (int j = 0; j < 3; ++j)
        #pragma unroll
        for (int mt = 0; mt < 5; ++mt)
            #pragma unroll
            for (int nt = 0; nt < NTC; ++nt) acc[j][mt][nt] = (f32x4)0.f;

    // depth-2 ks ring prefetch of weight fragments (R14 order: refill FIRST)
    bf16x8 ring[2][3][NTC];
    #pragma unroll
    for (int j = 0; j < 3; ++j)
        #pragma unroll
        for (int nt = 0; nt < NTC; ++nt) {
            ring[0][j][nt] = *(const bf16x8*)(wb[j][nt]);
            if (KS > 1) ring[1][j][nt] = *(const bf16x8*)(wb[j][nt] + 32);
        }

    #pragma unroll
    for (int ks = 0; ks < KS; ++ks) {
        bf16x8 bcur[3][NTC];
        #pragma unroll
        for (int j = 0; j < 3; ++j)
            #pragma unroll
            for (int nt = 0; nt < NTC; ++nt) bcur[j][nt] = ring[ks & 1][j][nt];
        if (ks + 2 < KS) {
            #pragma unroll
            for (int j = 0; j < 3; ++j)
                #pragma unroll
                for (int nt = 0; nt < NTC; ++nt)
                    ring[ks & 1][j][nt] =
                        *(const bf16x8*)(wb[j][nt] + (ks + 2)*32);
        }
        #pragma unroll
        for (int mt = 0; mt < 5; ++mt) {
            bf16x8 af = *(const bf16x8*)&sA[(mt*16 + r16)*SAS + ks*32 + quad*8];
            #pragma unroll
            for (int j = 0; j < 3; ++j)
                #pragma unroll
                for (int nt = 0; nt < NTC; ++nt)
                    acc[j][mt][nt] = __builtin_amdgcn_mfma_f32_16x16x32_bf16(
                        af, bcur[j][nt], acc[j][mt][nt], 0, 0, 0);
        }
    }

    if (GATE) __syncthreads();   // gate epilogue rewrites sA (r*h)

    float bv[NTC];
    #pragma unroll
    for (int nt = 0; nt < NTC; ++nt) bv[nt] = bias[sgo + nt*16 + r16];

    // T' fragments read here (not held across the K loop)
    bf16x8 tp[2][2];
    #pragma unroll
    for (int mt2 = 0; mt2 < 2; ++mt2)
        #pragma unroll
        for (int kk = 0; kk < 2; ++kk)
            tp[mt2][kk] = *(const bf16x8*)&g_tg[(mt2*16 + r16)*64 + kk*32 + quad*8];

    for (int b = 0; b < NB; ++b) {
        // scatter this batch's node rows into Ut (row = out col, col = j*19+n)
        #pragma unroll
        for (int j = 0; j < 3; ++j)
            #pragma unroll
            for (int mt = 0; mt < 5; ++mt)
                #pragma unroll
                for (int reg = 0; reg < 4; ++reg) {
                    int gm = mt*16 + quad*4 + reg;
                    int n  = gm - b*NN;
                    if (n >= 0 && n < NN) {
                        #pragma unroll
                        for (int nt = 0; nt < NTC; ++nt)
                            UtW[(nt*16 + r16)*UTS + j*NN + n] =
                                f2bf(acc[j][mt][nt][reg]);
                    }
                }
        // mixing: y = T' @ U
        f32x4 y[2][NTC];
        #pragma unroll
        for (int a = 0; a < 2; ++a)
            #pragma unroll
            for (int c = 0; c < NTC; ++c) y[a][c] = (f32x4)0.f;
        #pragma unroll
        for (int kk = 0; kk < 2; ++kk)
            #pragma unroll
            for (int nt = 0; nt < NTC; ++nt) {
                bf16x8 uf = *(const bf16x8*)&UtW[(nt*16 + r16)*UTS + kk*32 + quad*8];
                y[0][nt] = __builtin_amdgcn_mfma_f32_16x16x32_bf16(
                    tp[0][kk], uf, y[0][nt], 0, 0, 0);
                y[1][nt] = __builtin_amdgcn_mfma_f32_16x16x32_bf16(
                    tp[1][kk], uf, y[1][nt], 0, 0, 0);
            }
        // epilogue
        #pragma unroll
        for (int mt2 = 0; mt2 < 2; ++mt2)
            #pragma unroll
            for (int nt = 0; nt < NTC; ++nt)
                #pragma unroll
                for (int reg = 0; reg < 4; ++reg) {
                    int m = mt2*16 + quad*4 + reg;
                    if (m < NN) {
                        int o = sgo + nt*16 + r16;
                        float v = y[mt2][nt][reg] + bv[nt];
                        int row = b*NN + m;
                        if (GATE) {
                            float sg_ = 1.f/(1.f + __expf(-v));
                            if (o < HH)
                                sA[row*SAS + XW + o] =
                                    f2bf(sg_ * hload(&hL[row*HS + o]));
                            else
                                ub[row*HS + (o-HH)] = f2bf(sg_);
                        } else {
                            float c  = 2.f/(1.f + __expf(-2.f*v)) - 1.f;
                            float u  = bf2f(ub[row*HS + o]);
                            float ho = hload(&hL[row*HS + o]);
                            hstore(&hL[row*HS + o], u*ho + (1.f - u)*c);
                        }
                    }
                }
    }
}

__global__ __launch_bounds__(NT, 2) void dcgru_persistent(
    const float* __restrict__ ihs,
    const float* __restrict__ bg0, const float* __restrict__ bc0,
    const float* __restrict__ bg1, const float* __restrict__ bc1,
    const float* __restrict__ Wp, const float* __restrict__ bp,
    float* __restrict__ out)
{
    extern __shared__ char smem[];
    unsigned short* h0    = (unsigned short*)smem;                 // 20064
    float*          h1    = (float*)(smem + 20064);                // 40128
    unsigned short* sA    = (unsigned short*)(smem + 60192);       // 42240
    unsigned short* ub    = (unsigned short*)(smem + 102432);      // 20064
    unsigned short* Ut    = (unsigned short*)(smem + 122496);      // 36864
    float*          xprev = (float*)(smem + 159360);               // 304

    const int tid  = threadIdx.x;
    const int lane = tid & 63;
    const int w    = tid >> 6;          // 0..7
    const int bb   = blockIdx.x * NB;
    unsigned short* UtW = Ut + w*32*UTS;

    const unsigned short* BTg0 = g_wall + OFF_G0;
    const unsigned short* BTc0 = g_wall + OFF_C0;
    const unsigned short* BTg1 = g_wall + OFF_G1;
    const unsigned short* BTc1 = g_wall + OFF_C1;

    for (int i = tid; i < MR*HH; i += NT) {
        int row = i >> 7, f = i & 127;
        h0[row*HS + f] = f2bf(ihs[(size_t)bb*2432 + i]);
        h1[row*HS + f] = ihs[(size_t)(BATCH + bb)*2432 + i];
    }
    for (int i = tid; i < MR; i += NT) xprev[i] = 0.f;
    for (int i = lane; i < 32*UTS; i += 64) UtW[i] = 0;

    const float wp0 = Wp[lane], wp1 = Wp[64 + lane], bpv = bp[0];
    __syncthreads();

    for (int t = 0; t < SEQ; ++t) {
        // ---- layer 0: sA = [xprev | h0 | 0-pad]  (K = 160) ----
        for (int idx = tid; idx < MR*160; idx += NT) {
            int row = idx/160, c = idx - row*160;
            unsigned short v;
            if (c == 0)       v = f2bf(xprev[row]);
            else if (c <= HH) v = h0[row*HS + (c-1)];
            else              v = 0;
            sA[row*SAS + c] = v;
        }
        __syncthreads();
        gconv_phase<5,2,true ,1>(BTg0, bg0, h0, sA, ub, UtW, lane, w);
        __syncthreads();
        gconv_phase<5,1,false,1>(BTc0, bc0, h0, sA, ub, UtW, lane, w);
        __syncthreads();

        // ---- layer 1: sA = [h0 | h1]  (K = 256) ----
        for (int idx = tid; idx < MR*256; idx += NT) {
            int row = idx >> 8, c = idx & 255;
            sA[row*SAS + c] = (c < HH) ? h0[row*HS + c]
                                       : f2bf(h1[row*HS + (c-HH)]);
        }
        __syncthreads();
        gconv_phase<8,2,true ,HH>(BTg1, bg1, h1, sA, ub, UtW, lane, w);
        __syncthreads();
        gconv_phase<8,1,false,HH>(BTc1, bc1, h1, sA, ub, UtW, lane, w);
        __syncthreads();

        // ---- projection: wave w -> batch w>>1, half the nodes ----
        {
            int b  = w >> 1;
            int n0 = (w & 1) ? 10 : 0;
            int n1 = (w & 1) ? 19 : 10;
            for (int n = n0; n < n1; ++n) {
                int row = b*NN + n;
                float s = h1[row*HS + lane]*wp0 + h1[row*HS + 64 + lane]*wp1;
                #pragma unroll
                for (int off = 32; off; off >>= 1) s += __shfl_down(s, off, 64);
                if (lane == 0) {
                    float v = s + bpv;
                    out[((size_t)t*BATCH + bb + b)*NN + n] = v;
                    xprev[row] = v;
                }
            }
        }
        __syncthreads();
    }
}

// ---------------------------------------------------------------------------
extern "C" void kernel_launch(void* const* d_in, const int* in_sizes, int n_in,
                              void* d_out, int out_size, void* d_ws, size_t ws_size,
                              hipStream_t stream) {
    const float* ihs = (const float*)d_in[1];
    const float* S   = (const float*)d_in[2];
    const float* Wg0 = (const float*)d_in[3];
    const float* bg0 = (const float*)d_in[4];
    const float* Wc0 = (const float*)d_in[5];
    const float* bc0 = (const float*)d_in[6];
    const float* Wg1 = (const float*)d_in[7];
    const float* bg1 = (const float*)d_in[8];
    const float* Wc1 = (const float*)d_in[9];
    const float* bc1 = (const float*)d_in[10];
    const float* Wp  = (const float*)d_in[11];
    const float* bp  = (const float*)d_in[12];
    float* out = (float*)d_out;

    tprime_kernel<<<1, 256, 0, stream>>>(S);
    wconv_kernel<<<(3*256*160+255)/256, 256, 0, stream>>>(Wg0, 129, 256, 160, OFF_G0);
    wconv_kernel<<<(3*128*160+255)/256, 256, 0, stream>>>(Wc0, 129, 128, 160, OFF_C0);
    wconv_kernel<<<(3*256*256+255)/256, 256, 0, stream>>>(Wg1, 256, 256, 256, OFF_G1);
    wconv_kernel<<<(3*128*256+255)/256, 256, 0, stream>>>(Wc1, 256, 128, 256, OFF_C1);

    hipFuncSetAttribute((const void*)dcgru_persistent,
                        hipFuncAttributeMaxDynamicSharedMemorySize, LDS_BYTES);

    dcgru_persistent<<<NBLK, NT, LDS_BYTES, stream>>>(
        ihs, bg0, bc0, bg1, bc1, Wp, bp, out);
}